// Round 1
// baseline (105.832 us; speedup 1.0000x reference)
//
#include <hip/hip_runtime.h>
#include <hip/hip_bf16.h>

// ---------------------------------------------------------------------------
// NattenBlock: qkv GEMM -> 7x7 NATTEN (GQA 12q/4kv, D=64) -> out GEMM.
// 2048 pixels (2x32x32), d_model 768.
// Round 13: R12 structure (4 dispatches), two changes:
//  1. gemm_nt: K-loop converted to the minimal 2-phase double-buffered
//     pipeline (T3-minimal): BK=128, 2x16KB LDS per operand (64 KB total,
//     still 2 blocks/CU), issue next tile's global_load_lds BEFORE the
//     current tile's MFMAs, single "s_waitcnt vmcnt(0)" + raw s_barrier
//     per tile AFTER compute. Replaces the per-iter full-drain
//     __syncthreads pair that exposed the whole staging latency (3x/block).
//  2. convert: 3072 -> 1024 blocks, 3 float4/thread grid-stride (G11).
// Natten: staging-free MFMA (R9), unchanged.
// ---------------------------------------------------------------------------

typedef __attribute__((ext_vector_type(8))) __bf16 bf16x8;
typedef __attribute__((ext_vector_type(4))) float floatx4;
typedef unsigned short u16;

__device__ inline u16 f2bf(float f) {
    union { float f; unsigned u; } v; v.f = f;
    return (u16)((v.u + 0x7fff + ((v.u >> 16) & 1)) >> 16);   // RNE
}

__device__ inline void gl_lds16(const void* g, void* l) {
    __builtin_amdgcn_global_load_lds(
        (const __attribute__((address_space(1))) void*)g,
        (__attribute__((address_space(3))) void*)l, 16, 0, 0);
}

// fp32 -> bf16 for x (393216 f4), w_qkv (245760 f4), w_out (147456 f4).
// 1024 blocks x 256 threads x 3 f4 each = 786432 f4.
__global__ __launch_bounds__(256) void convert_kernel(
    const float* __restrict__ x, const float* __restrict__ w1,
    const float* __restrict__ w2, u16* __restrict__ xb,
    u16* __restrict__ w1b, u16* __restrict__ w2b)
{
    int t0 = blockIdx.x * 256 + threadIdx.x;   // 0..262143
    #pragma unroll
    for (int rep = 0; rep < 3; rep++) {
        int t = t0 + rep * 262144;
        const float* s; u16* d; int i = t;
        if (t < 393216)      { s = x;  d = xb; }
        else if (t < 638976) { s = w1; d = w1b; i = t - 393216; }
        else                 { s = w2; d = w2b; i = t - 638976; }
        float4 v = ((const float4*)s)[i];
        ushort4 o;
        o.x = f2bf(v.x); o.y = f2bf(v.y); o.z = f2bf(v.z); o.w = f2bf(v.w);
        ((ushort4*)d)[i] = o;
    }
}

// Flipped GEMM-NT: C'[dim,pix] = A[dim,K] @ B[pix,K]^T, bf16 in, fp32 acc.
// 64x64 tile, BK=128 as 4 kc sub-tiles of [64][32] (m97 layout), double
// buffered (2-phase pipeline). glds staging: waves 0,1 stage A (8 chunks of
// 1KB each), waves 2,3 stage B. 6 K-iterations (K=768). 64 KB LDS ->
// 2 blocks/CU.
// MODE 1 (qkv): dim<1024 -> qkvb[pix*1024+dim] (ushort4); dim>=1024 ->
//   vT[(dim-1024)*2048+pix]. MODE 0 (out): out[pix*768+dim] float4.
template<int MODE>
__global__ __launch_bounds__(256) void gemm_nt(
    const u16* __restrict__ A, const u16* __restrict__ B,
    float* __restrict__ out, u16* __restrict__ Cq, u16* __restrict__ vT,
    int K)
{
    __shared__ __align__(16) u16 As[2][4 * 2048];   // 2 x 16 KB [kc][row][32]
    __shared__ __align__(16) u16 Bs[2][4 * 2048];   // 2 x 16 KB
    const int tid = threadIdx.x;
    const int lane = tid & 63;
    const int wave = tid >> 6;
    const int bm = blockIdx.y * 64;   // dim tile (A rows)
    const int bn = blockIdx.x * 64;   // pixel tile (B rows)
    const int qr = (wave >> 1) * 32;
    const int qc = (wave & 1) * 32;

    floatx4 acc[2][2] = {};

    const bool isA  = (wave < 2);
    const u16* Xsrc = isA ? A : B;
    const int   bx  = isA ? bm : bn;
    u16* Xbase      = isA ? &As[0][0] : &Bs[0][0];
    const int half  = wave & 1;
    const int l2 = lane >> 2;            // row within 16-row group
    const int l3 = (lane & 3) * 8;       // k-oct within 32
    int gofs[8], lofs[8];
    #pragma unroll
    for (int cc = 0; cc < 8; cc++) {
        int c = half * 8 + cc, kc = c & 3, rg = c >> 2;
        gofs[cc] = (bx + rg * 16 + l2) * K + kc * 32 + l3;
        lofs[cc] = kc * 2048 + rg * 512;
    }

    const int fr = lane & 15;
    const int fk = (lane >> 4) * 8;

    const int NIT = K >> 7;              // 6 for K=768
    int cur = 0;

    // prologue: stage tile 0 into buffer 0, publish.
    #pragma unroll
    for (int cc = 0; cc < 8; cc++)
        gl_lds16(Xsrc + gofs[cc], Xbase + lofs[cc]);
    asm volatile("s_waitcnt vmcnt(0)" ::: "memory");
    __builtin_amdgcn_s_barrier();

    for (int it = 0; it < NIT; ++it) {
        // issue next tile's loads first (overlap with this tile's compute);
        // target buffer was last READ at it-1, protected by that iteration's
        // trailing barrier.
        if (it + 1 < NIT) {
            u16* dst = Xbase + ((cur ^ 1) << 13);
            const int k0 = (it + 1) << 7;
            #pragma unroll
            for (int cc = 0; cc < 8; cc++)
                gl_lds16(Xsrc + gofs[cc] + k0, dst + lofs[cc]);
        }
        const u16* as = &As[0][0] + (cur << 13);
        const u16* bs = &Bs[0][0] + (cur << 13);
        #pragma unroll
        for (int kc = 0; kc < 4; kc++) {
            bf16x8 af0 = *(const bf16x8*)&as[kc * 2048 + (qr +      fr) * 32 + fk];
            bf16x8 af1 = *(const bf16x8*)&as[kc * 2048 + (qr + 16 + fr) * 32 + fk];
            bf16x8 bf0 = *(const bf16x8*)&bs[kc * 2048 + (qc +      fr) * 32 + fk];
            bf16x8 bf1 = *(const bf16x8*)&bs[kc * 2048 + (qc + 16 + fr) * 32 + fk];
            acc[0][0] = __builtin_amdgcn_mfma_f32_16x16x32_bf16(af0, bf0, acc[0][0], 0, 0, 0);
            acc[0][1] = __builtin_amdgcn_mfma_f32_16x16x32_bf16(af0, bf1, acc[0][1], 0, 0, 0);
            acc[1][0] = __builtin_amdgcn_mfma_f32_16x16x32_bf16(af1, bf0, acc[1][0], 0, 0, 0);
            acc[1][1] = __builtin_amdgcn_mfma_f32_16x16x32_bf16(af1, bf1, acc[1][1], 0, 0, 0);
        }
        // wait for the 8 glds issued THIS iteration (next tile's data) and
        // publish to all waves. The wait overlapped with the 16 MFMAs above.
        asm volatile("s_waitcnt vmcnt(0)" ::: "memory");
        __builtin_amdgcn_s_barrier();
        cur ^= 1;
    }

    // C/D layout: col(=pixel) = lane&15, row(=dim) = (lane>>4)*4 + r.
    const int cr = (lane >> 4) * 4;
    const int ccol = lane & 15;
    #pragma unroll
    for (int i = 0; i < 2; i++) {
        #pragma unroll
        for (int j = 0; j < 2; j++) {
            const int row0 = bm + qr + i * 16 + cr;       // dim
            const int col  = bn + qc + j * 16 + ccol;     // pixel
            if (MODE == 0) {
                float4 w = {acc[i][j][0], acc[i][j][1], acc[i][j][2], acc[i][j][3]};
                *(float4*)&out[(size_t)col * 768 + row0] = w;
            } else {
                if (row0 < 1024) {
                    ushort4 w;
                    w.x = f2bf(acc[i][j][0]); w.y = f2bf(acc[i][j][1]);
                    w.z = f2bf(acc[i][j][2]); w.w = f2bf(acc[i][j][3]);
                    *(ushort4*)&Cq[(size_t)col * 1024 + row0] = w;
                } else {
                    #pragma unroll
                    for (int r = 0; r < 4; r++)
                        vT[(size_t)(row0 + r - 1024) * 2048 + col] = f2bf(acc[i][j][r]);
                }
            }
        }
    }
}

// NATTEN 7x7 MFMA, zero staging (R9). Block = (q-head h, 8x8 pixel tile),
// 4 waves x 16 queries. Rows wu_i..wu_i+13 (wu_i = clip(ti-3,0,18)), cols
// oj..oj+15 (oj = clip4(tj-3) in {0,4,12,16}) cover every query's window.
__global__ __launch_bounds__(256) void natten_mfma(
    const u16* __restrict__ qkv, const u16* __restrict__ vT,
    u16* __restrict__ o)
{
    __shared__ __align__(16) u16 Pw[4 * 512];   // 4 KB, per-wave P^T chunks
    const int h  = blockIdx.x;        // 0..11
    const int tb = blockIdx.y;        // 0..31
    const int g  = h & 3;             // kv head
    const int batch = tb >> 4;
    const int ti = ((tb >> 2) & 3) * 8;
    const int tj = (tb & 3) * 8;
    const int wu_i = min(max(ti - 3, 0), 18);
    const int oj   = min(max(tj - 3, 0) & ~3, 16);
    const int lane = threadIdx.x & 63, wave = threadIdx.x >> 6;
    const int pixbase = batch << 10;

    const int fr = lane & 15;
    const int fk = (lane >> 4) * 8;   // 0,8,16,24

    bf16x8 aq0, aq1;
    {
        int qq = wave * 16 + fr;
        int pixq = pixbase + (ti + (qq >> 3)) * 32 + tj + (qq & 7);
        const u16* qp = &qkv[(size_t)pixq * 1024 + h * 64];
        aq0 = *(const bf16x8*)(qp + fk);
        aq1 = *(const bf16x8*)(qp + 32 + fk);
    }

    bool colok[4]; int tlo[4], thi[4];
    #pragma unroll
    for (int r = 0; r < 4; r++) {
        int qq = wave * 16 + (lane >> 4) * 4 + r;
        int qi = ti + (qq >> 3), qj = tj + (qq & 7);
        int si = min(max(qi - 3, 0), 25);
        int sj = min(max(qj - 3, 0), 25);
        colok[r] = (oj + fr >= sj) && (oj + fr <= sj + 6);
        tlo[r] = si - wu_i; thi[r] = tlo[r] + 6;
    }

    float s[14][4];
    float mx[4] = {-1e30f, -1e30f, -1e30f, -1e30f};
    #pragma unroll
    for (int t = 0; t < 14; t++) {
        int kp = pixbase + (wu_i + t) * 32 + oj + fr;
        const u16* krow = &qkv[(size_t)kp * 1024 + 768 + g * 64];
        bf16x8 bk0 = *(const bf16x8*)(krow + fk);
        bf16x8 bk1 = *(const bf16x8*)(krow + 32 + fk);
        floatx4 a4 = {};
        a4 = __builtin_amdgcn_mfma_f32_16x16x32_bf16(aq0, bk0, a4, 0, 0, 0);
        a4 = __builtin_amdgcn_mfma_f32_16x16x32_bf16(aq1, bk1, a4, 0, 0, 0);
        #pragma unroll
        for (int r = 0; r < 4; r++) {
            bool v = colok[r] && (t >= tlo[r]) && (t <= thi[r]);
            s[t][r] = v ? a4[r] * 0.125f : -1e30f;
            mx[r] = fmaxf(mx[r], s[t][r]);
        }
    }
    #pragma unroll
    for (int r = 0; r < 4; r++) {
        mx[r] = fmaxf(mx[r], __shfl_xor(mx[r], 1));
        mx[r] = fmaxf(mx[r], __shfl_xor(mx[r], 2));
        mx[r] = fmaxf(mx[r], __shfl_xor(mx[r], 4));
        mx[r] = fmaxf(mx[r], __shfl_xor(mx[r], 8));
    }
    float l[4] = {0.f, 0.f, 0.f, 0.f};
    #pragma unroll
    for (int t = 0; t < 14; t++)
        #pragma unroll
        for (int r = 0; r < 4; r++) {
            float p = __expf(s[t][r] - mx[r]);
            s[t][r] = p; l[r] += p;
        }
    #pragma unroll
    for (int r = 0; r < 4; r++) {
        l[r] += __shfl_xor(l[r], 1);
        l[r] += __shfl_xor(l[r], 2);
        l[r] += __shfl_xor(l[r], 4);
        l[r] += __shfl_xor(l[r], 8);
    }
    float rinv[4];
    #pragma unroll
    for (int r = 0; r < 4; r++) rinv[r] = 1.0f / l[r];

    u16* pw = &Pw[wave * 512];
    floatx4 oacc[4] = {};
    const int vrow = (fk >= 16) ? 1 : 0;
    const int vcol = oj + (fk & 8);
    #pragma unroll
    for (int kc = 0; kc < 7; kc++) {
        #pragma unroll
        for (int tt = 0; tt < 2; tt++) {
            int t = kc * 2 + tt;
            #pragma unroll
            for (int r = 0; r < 4; r++)
                pw[((lane >> 4) * 4 + r) * 32 + tt * 16 + fr] =
                    f2bf(s[t][r] * rinv[r]);
        }
        bf16x8 bp = *(const bf16x8*)&pw[fr * 32 + fk];
        const int vpix = pixbase + (wu_i + kc * 2 + vrow) * 32 + vcol;
        #pragma unroll
        for (int u = 0; u < 4; u++) {
            const u16* vp = &vT[(size_t)(g * 64 + u * 16 + fr) * 2048 + vpix];
            union { ushort4 q[2]; bf16x8 v; } av;
            av.q[0] = *(const ushort4*)vp;
            av.q[1] = *(const ushort4*)(vp + 4);
            oacc[u] = __builtin_amdgcn_mfma_f32_16x16x32_bf16(av.v, bp, oacc[u], 0, 0, 0);
        }
    }

    {
        int qq = wave * 16 + fr;
        int pixq = pixbase + (ti + (qq >> 3)) * 32 + tj + (qq & 7);
        u16* op = &o[(size_t)pixq * 768 + h * 64];
        #pragma unroll
        for (int u = 0; u < 4; u++) {
            ushort4 w;
            w.x = f2bf(oacc[u][0]); w.y = f2bf(oacc[u][1]);
            w.z = f2bf(oacc[u][2]); w.w = f2bf(oacc[u][3]);
            *(ushort4*)(op + u * 16 + (lane >> 4) * 4) = w;
        }
    }
}

extern "C" void kernel_launch(void* const* d_in, const int* in_sizes, int n_in,
                              void* d_out, int out_size, void* d_ws, size_t ws_size,
                              hipStream_t stream)
{
    const float* x     = (const float*)d_in[0];   // (2048, 768)
    const float* w_qkv = (const float*)d_in[1];   // (1280, 768)
    const float* w_out = (const float*)d_in[2];   // (768, 768)
    float* out = (float*)d_out;                   // (2048, 768) fp32

    char* ws = (char*)d_ws;
    u16* qkvb = (u16*)ws; ws += (size_t)2048 * 1024 * 2;      // q|k bf16, 4 MB
    u16* vTb  = (u16*)ws; ws += (size_t)256 * 2048 * 2 + 64;  // v^T bf16, 1 MB
    u16* xb   = (u16*)ws; ws += (size_t)2048 * 768 * 2;       // 3 MB
    u16* w1b  = (u16*)ws; ws += (size_t)1280 * 768 * 2;       // 2 MB
    u16* w2b  = (u16*)ws; ws += (size_t)768 * 768 * 2;        // 1.1 MB
    u16* ob   = (u16*)ws;                                     // 3 MB

    convert_kernel<<<dim3(1024), dim3(256), 0, stream>>>(x, w_qkv, w_out, xb, w1b, w2b);

    // qkv^T = w_qkv @ x^T -> qkvb[pix][dim<1024] + vT[dim-1024][pix]
    gemm_nt<1><<<dim3(2048 / 64, 1280 / 64), dim3(256), 0, stream>>>(
        w1b, xb, nullptr, qkvb, vTb, 768);

    natten_mfma<<<dim3(12, 32), dim3(256), 0, stream>>>(qkvb, vTb, ob);

    // out^T = w_out @ o^T -> out[pix][dim] (float4 on dim axis)
    gemm_nt<0><<<dim3(2048 / 64, 768 / 64), dim3(256), 0, stream>>>(
        w2b, ob, out, nullptr, nullptr, 768);
}

// Round 3
// 103.721 us; speedup vs baseline: 1.0204x; 1.0204x over previous
//
#include <hip/hip_runtime.h>
#include <hip/hip_bf16.h>

// ---------------------------------------------------------------------------
// NattenBlock: qkv GEMM -> 7x7 NATTEN (GQA 12q/4kv, D=64) -> out GEMM.
// 2048 pixels (2x32x32), d_model 768.
// Round 15 == Round 14 resubmit (container infra failure, kernel unmeasured):
// R13 structure (4 dispatches, 2-phase dbuf GEMM pipeline), two
// occupancy/locality changes to gemm_nt:
//  1. BK 128 -> 64, LDS 64 KB -> 32 KB/block -> 5 blocks/CU. Kills GEMM1's
//     ragged second round (640 blocks > 512 resident slots at 2/CU) and
//     gives 20 waves/CU of cross-block latency hiding.
//  2. Bijective XCD swizzle (T1) on the flattened block index (both grids
//     %8==0): each XCD works a contiguous chunk -> A-panels hit its L2.
// Natten: staging-free MFMA (R9), unchanged. Convert: unchanged.
// ---------------------------------------------------------------------------

typedef __attribute__((ext_vector_type(8))) __bf16 bf16x8;
typedef __attribute__((ext_vector_type(4))) float floatx4;
typedef unsigned short u16;

__device__ inline u16 f2bf(float f) {
    union { float f; unsigned u; } v; v.f = f;
    return (u16)((v.u + 0x7fff + ((v.u >> 16) & 1)) >> 16);   // RNE
}

__device__ inline void gl_lds16(const void* g, void* l) {
    __builtin_amdgcn_global_load_lds(
        (const __attribute__((address_space(1))) void*)g,
        (__attribute__((address_space(3))) void*)l, 16, 0, 0);
}

// fp32 -> bf16 for x (393216 f4), w_qkv (245760 f4), w_out (147456 f4).
// 1024 blocks x 256 threads x 3 f4 each = 786432 f4.
__global__ __launch_bounds__(256) void convert_kernel(
    const float* __restrict__ x, const float* __restrict__ w1,
    const float* __restrict__ w2, u16* __restrict__ xb,
    u16* __restrict__ w1b, u16* __restrict__ w2b)
{
    int t0 = blockIdx.x * 256 + threadIdx.x;   // 0..262143
    #pragma unroll
    for (int rep = 0; rep < 3; rep++) {
        int t = t0 + rep * 262144;
        const float* s; u16* d; int i = t;
        if (t < 393216)      { s = x;  d = xb; }
        else if (t < 638976) { s = w1; d = w1b; i = t - 393216; }
        else                 { s = w2; d = w2b; i = t - 638976; }
        float4 v = ((const float4*)s)[i];
        ushort4 o;
        o.x = f2bf(v.x); o.y = f2bf(v.y); o.z = f2bf(v.z); o.w = f2bf(v.w);
        ((ushort4*)d)[i] = o;
    }
}

// Flipped GEMM-NT: C'[dim,pix] = A[dim,K] @ B[pix,K]^T, bf16 in, fp32 acc.
// 64x64 tile, BK=64 as 2 kc sub-tiles of [64][32] (m97 layout), double
// buffered (2-phase pipeline). glds staging: waves 0,1 stage A (4 chunks of
// 1KB each), waves 2,3 stage B. 12 K-iterations (K=768). 32 KB LDS ->
// 5 blocks/CU, all blocks resident for both launches.
// MODE 1 (qkv): dim<1024 -> qkvb[pix*1024+dim] (ushort4); dim>=1024 ->
//   vT[(dim-1024)*2048+pix]. MODE 0 (out): out[pix*768+dim] float4.
template<int MODE>
__global__ __launch_bounds__(256) void gemm_nt(
    const u16* __restrict__ A, const u16* __restrict__ B,
    float* __restrict__ out, u16* __restrict__ Cq, u16* __restrict__ vT,
    int K)
{
    __shared__ __align__(16) u16 As[2][2 * 2048];   // 2 x 8 KB [kc][row][32]
    __shared__ __align__(16) u16 Bs[2][2 * 2048];   // 2 x 8 KB
    const int tid = threadIdx.x;
    const int lane = tid & 63;
    const int wave = tid >> 6;

    // Bijective XCD swizzle (T1): nwg % 8 == 0 for both launches (640, 384).
    const unsigned nwg = gridDim.x * gridDim.y;
    const unsigned cpx = nwg >> 3;
    unsigned lid = blockIdx.y * gridDim.x + blockIdx.x;
    lid = (lid & 7) * cpx + (lid >> 3);
    const int bm = (int)(lid / gridDim.x) * 64;   // dim tile (A rows)
    const int bn = (int)(lid % gridDim.x) * 64;   // pixel tile (B rows)

    const int qr = (wave >> 1) * 32;
    const int qc = (wave & 1) * 32;

    floatx4 acc[2][2] = {};

    const bool isA  = (wave < 2);
    const u16* Xsrc = isA ? A : B;
    const int   bx  = isA ? bm : bn;
    u16* Xbase      = isA ? &As[0][0] : &Bs[0][0];
    const int half  = wave & 1;
    const int l2 = lane >> 2;            // row within 16-row group
    const int l3 = (lane & 3) * 8;       // k-oct within 32
    int gofs[4], lofs[4];
    #pragma unroll
    for (int cc = 0; cc < 4; cc++) {
        int c = half * 4 + cc, kc = c & 1, rg = c >> 1;
        gofs[cc] = (bx + rg * 16 + l2) * K + kc * 32 + l3;
        lofs[cc] = kc * 2048 + rg * 512;
    }

    const int fr = lane & 15;
    const int fk = (lane >> 4) * 8;

    const int NIT = K >> 6;              // 12 for K=768
    int cur = 0;

    // prologue: stage tile 0 into buffer 0, publish.
    #pragma unroll
    for (int cc = 0; cc < 4; cc++)
        gl_lds16(Xsrc + gofs[cc], Xbase + lofs[cc]);
    asm volatile("s_waitcnt vmcnt(0)" ::: "memory");
    __builtin_amdgcn_s_barrier();

    for (int it = 0; it < NIT; ++it) {
        // issue next tile's loads first (overlap with this tile's compute);
        // target buffer was last READ at it-1, protected by that iteration's
        // trailing barrier.
        if (it + 1 < NIT) {
            u16* dst = Xbase + ((cur ^ 1) << 12);
            const int k0 = (it + 1) << 6;
            #pragma unroll
            for (int cc = 0; cc < 4; cc++)
                gl_lds16(Xsrc + gofs[cc] + k0, dst + lofs[cc]);
        }
        const u16* as = &As[0][0] + (cur << 12);
        const u16* bs = &Bs[0][0] + (cur << 12);
        #pragma unroll
        for (int kc = 0; kc < 2; kc++) {
            bf16x8 af0 = *(const bf16x8*)&as[kc * 2048 + (qr +      fr) * 32 + fk];
            bf16x8 af1 = *(const bf16x8*)&as[kc * 2048 + (qr + 16 + fr) * 32 + fk];
            bf16x8 bf0 = *(const bf16x8*)&bs[kc * 2048 + (qc +      fr) * 32 + fk];
            bf16x8 bf1 = *(const bf16x8*)&bs[kc * 2048 + (qc + 16 + fr) * 32 + fk];
            acc[0][0] = __builtin_amdgcn_mfma_f32_16x16x32_bf16(af0, bf0, acc[0][0], 0, 0, 0);
            acc[0][1] = __builtin_amdgcn_mfma_f32_16x16x32_bf16(af0, bf1, acc[0][1], 0, 0, 0);
            acc[1][0] = __builtin_amdgcn_mfma_f32_16x16x32_bf16(af1, bf0, acc[1][0], 0, 0, 0);
            acc[1][1] = __builtin_amdgcn_mfma_f32_16x16x32_bf16(af1, bf1, acc[1][1], 0, 0, 0);
        }
        // wait for the 4 glds issued THIS iteration (next tile's data) and
        // publish to all waves. The wait overlapped with the 8 MFMAs above.
        asm volatile("s_waitcnt vmcnt(0)" ::: "memory");
        __builtin_amdgcn_s_barrier();
        cur ^= 1;
    }

    // C/D layout: col(=pixel) = lane&15, row(=dim) = (lane>>4)*4 + r.
    const int cr = (lane >> 4) * 4;
    const int ccol = lane & 15;
    #pragma unroll
    for (int i = 0; i < 2; i++) {
        #pragma unroll
        for (int j = 0; j < 2; j++) {
            const int row0 = bm + qr + i * 16 + cr;       // dim
            const int col  = bn + qc + j * 16 + ccol;     // pixel
            if (MODE == 0) {
                float4 w = {acc[i][j][0], acc[i][j][1], acc[i][j][2], acc[i][j][3]};
                *(float4*)&out[(size_t)col * 768 + row0] = w;
            } else {
                if (row0 < 1024) {
                    ushort4 w;
                    w.x = f2bf(acc[i][j][0]); w.y = f2bf(acc[i][j][1]);
                    w.z = f2bf(acc[i][j][2]); w.w = f2bf(acc[i][j][3]);
                    *(ushort4*)&Cq[(size_t)col * 1024 + row0] = w;
                } else {
                    #pragma unroll
                    for (int r = 0; r < 4; r++)
                        vT[(size_t)(row0 + r - 1024) * 2048 + col] = f2bf(acc[i][j][r]);
                }
            }
        }
    }
}

// NATTEN 7x7 MFMA, zero staging (R9). Block = (q-head h, 8x8 pixel tile),
// 4 waves x 16 queries. Rows wu_i..wu_i+13 (wu_i = clip(ti-3,0,18)), cols
// oj..oj+15 (oj = clip4(tj-3) in {0,4,12,16}) cover every query's window.
__global__ __launch_bounds__(256) void natten_mfma(
    const u16* __restrict__ qkv, const u16* __restrict__ vT,
    u16* __restrict__ o)
{
    __shared__ __align__(16) u16 Pw[4 * 512];   // 4 KB, per-wave P^T chunks
    const int h  = blockIdx.x;        // 0..11
    const int tb = blockIdx.y;        // 0..31
    const int g  = h & 3;             // kv head
    const int batch = tb >> 4;
    const int ti = ((tb >> 2) & 3) * 8;
    const int tj = (tb & 3) * 8;
    const int wu_i = min(max(ti - 3, 0), 18);
    const int oj   = min(max(tj - 3, 0) & ~3, 16);
    const int lane = threadIdx.x & 63, wave = threadIdx.x >> 6;
    const int pixbase = batch << 10;

    const int fr = lane & 15;
    const int fk = (lane >> 4) * 8;   // 0,8,16,24

    bf16x8 aq0, aq1;
    {
        int qq = wave * 16 + fr;
        int pixq = pixbase + (ti + (qq >> 3)) * 32 + tj + (qq & 7);
        const u16* qp = &qkv[(size_t)pixq * 1024 + h * 64];
        aq0 = *(const bf16x8*)(qp + fk);
        aq1 = *(const bf16x8*)(qp + 32 + fk);
    }

    bool colok[4]; int tlo[4], thi[4];
    #pragma unroll
    for (int r = 0; r < 4; r++) {
        int qq = wave * 16 + (lane >> 4) * 4 + r;
        int qi = ti + (qq >> 3), qj = tj + (qq & 7);
        int si = min(max(qi - 3, 0), 25);
        int sj = min(max(qj - 3, 0), 25);
        colok[r] = (oj + fr >= sj) && (oj + fr <= sj + 6);
        tlo[r] = si - wu_i; thi[r] = tlo[r] + 6;
    }

    float s[14][4];
    float mx[4] = {-1e30f, -1e30f, -1e30f, -1e30f};
    #pragma unroll
    for (int t = 0; t < 14; t++) {
        int kp = pixbase + (wu_i + t) * 32 + oj + fr;
        const u16* krow = &qkv[(size_t)kp * 1024 + 768 + g * 64];
        bf16x8 bk0 = *(const bf16x8*)(krow + fk);
        bf16x8 bk1 = *(const bf16x8*)(krow + 32 + fk);
        floatx4 a4 = {};
        a4 = __builtin_amdgcn_mfma_f32_16x16x32_bf16(aq0, bk0, a4, 0, 0, 0);
        a4 = __builtin_amdgcn_mfma_f32_16x16x32_bf16(aq1, bk1, a4, 0, 0, 0);
        #pragma unroll
        for (int r = 0; r < 4; r++) {
            bool v = colok[r] && (t >= tlo[r]) && (t <= thi[r]);
            s[t][r] = v ? a4[r] * 0.125f : -1e30f;
            mx[r] = fmaxf(mx[r], s[t][r]);
        }
    }
    #pragma unroll
    for (int r = 0; r < 4; r++) {
        mx[r] = fmaxf(mx[r], __shfl_xor(mx[r], 1));
        mx[r] = fmaxf(mx[r], __shfl_xor(mx[r], 2));
        mx[r] = fmaxf(mx[r], __shfl_xor(mx[r], 4));
        mx[r] = fmaxf(mx[r], __shfl_xor(mx[r], 8));
    }
    float l[4] = {0.f, 0.f, 0.f, 0.f};
    #pragma unroll
    for (int t = 0; t < 14; t++)
        #pragma unroll
        for (int r = 0; r < 4; r++) {
            float p = __expf(s[t][r] - mx[r]);
            s[t][r] = p; l[r] += p;
        }
    #pragma unroll
    for (int r = 0; r < 4; r++) {
        l[r] += __shfl_xor(l[r], 1);
        l[r] += __shfl_xor(l[r], 2);
        l[r] += __shfl_xor(l[r], 4);
        l[r] += __shfl_xor(l[r], 8);
    }
    float rinv[4];
    #pragma unroll
    for (int r = 0; r < 4; r++) rinv[r] = 1.0f / l[r];

    u16* pw = &Pw[wave * 512];
    floatx4 oacc[4] = {};
    const int vrow = (fk >= 16) ? 1 : 0;
    const int vcol = oj + (fk & 8);
    #pragma unroll
    for (int kc = 0; kc < 7; kc++) {
        #pragma unroll
        for (int tt = 0; tt < 2; tt++) {
            int t = kc * 2 + tt;
            #pragma unroll
            for (int r = 0; r < 4; r++)
                pw[((lane >> 4) * 4 + r) * 32 + tt * 16 + fr] =
                    f2bf(s[t][r] * rinv[r]);
        }
        bf16x8 bp = *(const bf16x8*)&pw[fr * 32 + fk];
        const int vpix = pixbase + (wu_i + kc * 2 + vrow) * 32 + vcol;
        #pragma unroll
        for (int u = 0; u < 4; u++) {
            const u16* vp = &vT[(size_t)(g * 64 + u * 16 + fr) * 2048 + vpix];
            union { ushort4 q[2]; bf16x8 v; } av;
            av.q[0] = *(const ushort4*)vp;
            av.q[1] = *(const ushort4*)(vp + 4);
            oacc[u] = __builtin_amdgcn_mfma_f32_16x16x32_bf16(av.v, bp, oacc[u], 0, 0, 0);
        }
    }

    {
        int qq = wave * 16 + fr;
        int pixq = pixbase + (ti + (qq >> 3)) * 32 + tj + (qq & 7);
        u16* op = &o[(size_t)pixq * 768 + h * 64];
        #pragma unroll
        for (int u = 0; u < 4; u++) {
            ushort4 w;
            w.x = f2bf(oacc[u][0]); w.y = f2bf(oacc[u][1]);
            w.z = f2bf(oacc[u][2]); w.w = f2bf(oacc[u][3]);
            *(ushort4*)(op + u * 16 + (lane >> 4) * 4) = w;
        }
    }
}

extern "C" void kernel_launch(void* const* d_in, const int* in_sizes, int n_in,
                              void* d_out, int out_size, void* d_ws, size_t ws_size,
                              hipStream_t stream)
{
    const float* x     = (const float*)d_in[0];   // (2048, 768)
    const float* w_qkv = (const float*)d_in[1];   // (1280, 768)
    const float* w_out = (const float*)d_in[2];   // (768, 768)
    float* out = (float*)d_out;                   // (2048, 768) fp32

    char* ws = (char*)d_ws;
    u16* qkvb = (u16*)ws; ws += (size_t)2048 * 1024 * 2;      // q|k bf16, 4 MB
    u16* vTb  = (u16*)ws; ws += (size_t)256 * 2048 * 2 + 64;  // v^T bf16, 1 MB
    u16* xb   = (u16*)ws; ws += (size_t)2048 * 768 * 2;       // 3 MB
    u16* w1b  = (u16*)ws; ws += (size_t)1280 * 768 * 2;       // 2 MB
    u16* w2b  = (u16*)ws; ws += (size_t)768 * 768 * 2;        // 1.1 MB
    u16* ob   = (u16*)ws;                                     // 3 MB

    convert_kernel<<<dim3(1024), dim3(256), 0, stream>>>(x, w_qkv, w_out, xb, w1b, w2b);

    // qkv^T = w_qkv @ x^T -> qkvb[pix][dim<1024] + vT[dim-1024][pix]
    gemm_nt<1><<<dim3(2048 / 64, 1280 / 64), dim3(256), 0, stream>>>(
        w1b, xb, nullptr, qkvb, vTb, 768);

    natten_mfma<<<dim3(12, 32), dim3(256), 0, stream>>>(qkvb, vTb, ob);

    // out^T = w_out @ o^T -> out[pix][dim] (float4 on dim axis)
    gemm_nt<0><<<dim3(2048 / 64, 768 / 64), dim3(256), 0, stream>>>(
        w2b, ob, out, nullptr, nullptr, 768);
}